// Round 14
// baseline (462.856 us; speedup 1.0000x reference)
//
#include <hip/hip_runtime.h>
#include <hip/hip_fp16.h>
#include <math.h>

#define N_NODES 200000
#define N_EDGES 6400000
#define NEG_SLOPE 0.01f
#define EPS_F 1e-5f

// bucket partition params
#define BSHIFT 8
#define BSIZE 256                      // nodes per bucket
#define NBKT 782                       // ceil(N_NODES / 256)
#define NBIN 784                       // padded bin count
#define CHP 4096                       // edges per place chunk (r12 proven)
#define NCHUNK ((N_EDGES + CHP - 1) / CHP)   // 1563
#define CIPT 7                         // colscan chunks per thread (256*7 >= 1563)

// k_acc_sp params
#define SACC 3                         // splits per bucket
#define CHA 3072                       // edges per sort pass (24 KB)

__device__ __forceinline__ float sigmoidf_(float x) { return 1.0f / (1.0f + expf(-x)); }

__device__ __forceinline__ void unpack_h8(uint4 hv, float* f) {
    __half2* hp = (__half2*)&hv;
    float2 f0 = __half22float2(hp[0]);
    float2 f1 = __half22float2(hp[1]);
    float2 f2 = __half22float2(hp[2]);
    float2 f3 = __half22float2(hp[3]);
    f[0] = f0.x; f[1] = f0.y; f[2] = f1.x; f[3] = f1.y;
    f[4] = f2.x; f[5] = f2.y; f[6] = f3.x; f[7] = f3.y;
}

// ---------------- K1: per-node GRU + x1_raw + stats1 ----------------
__global__ void k_gru(const float* __restrict__ x,
                      const float* __restrict__ w_ih, const float* __restrict__ w_hh,
                      const float* __restrict__ b_ih, const float* __restrict__ b_hh,
                      float* __restrict__ x1_raw, float* __restrict__ stats1) {
    __shared__ float xs[5 * 256];
    int base = blockIdx.x * (5 * 256);
    for (int j = threadIdx.x; j < 5 * 256; j += 256) {
        int g = base + j;
        if (g < 5 * N_NODES) xs[j] = x[g];
    }
    __syncthreads();
    int i = blockIdx.x * blockDim.x + threadIdx.x;
    float vals[9];
    if (i < N_NODES) {
        float xv[5];
#pragma unroll
        for (int j = 0; j < 5; ++j) xv[j] = xs[threadIdx.x * 5 + j];
        float wih[6], whh[12], bih[6], bhh[6];
#pragma unroll
        for (int j = 0; j < 6; ++j) { wih[j] = w_ih[j]; bih[j] = b_ih[j]; bhh[j] = b_hh[j]; }
#pragma unroll
        for (int j = 0; j < 12; ++j) whh[j] = w_hh[j];
        float h0 = 0.f, h1 = 0.f;
#pragma unroll
        for (int t = 0; t < 4; ++t) {
            float xt = xv[t];
            float gi[6], gh[6];
#pragma unroll
            for (int j = 0; j < 6; ++j) {
                gi[j] = xt * wih[j] + bih[j];
                gh[j] = h0 * whh[2 * j] + h1 * whh[2 * j + 1] + bhh[j];
            }
            float r0 = sigmoidf_(gi[0] + gh[0]);
            float r1 = sigmoidf_(gi[1] + gh[1]);
            float z0 = sigmoidf_(gi[2] + gh[2]);
            float z1 = sigmoidf_(gi[3] + gh[3]);
            float n0 = tanhf(gi[4] + r0 * gh[4]);
            float n1 = tanhf(gi[5] + r1 * gh[5]);
            h0 = (1.f - z0) * n0 + z0 * h0;
            h1 = (1.f - z1) * n1 + z1 * h1;
            vals[2 * t] = h0;
            vals[2 * t + 1] = h1;
        }
        vals[8] = xv[4];
#pragma unroll
        for (int c = 0; c < 9; ++c) x1_raw[(size_t)i * 9 + c] = vals[c];
    } else {
#pragma unroll
        for (int c = 0; c < 9; ++c) vals[c] = 0.f;
    }
    __shared__ float sh[18];
    __syncthreads();
    if (threadIdx.x < 18) sh[threadIdx.x] = 0.f;
    __syncthreads();
#pragma unroll
    for (int c = 0; c < 9; ++c) {
        float s = vals[c], q = vals[c] * vals[c];
#pragma unroll
        for (int off = 32; off > 0; off >>= 1) {
            s += __shfl_down(s, off, 64);
            q += __shfl_down(q, off, 64);
        }
        if ((threadIdx.x & 63) == 0) { atomicAdd(&sh[c], s); atomicAdd(&sh[9 + c], q); }
    }
    __syncthreads();
    if (threadIdx.x < 18) atomicAdd(&stats1[threadIdx.x], sh[threadIdx.x]);
}

// ---------------- per-chunk histogram -> cmat (no global atomics) ----------------
__global__ void k_hist2(const int* __restrict__ col, unsigned short* __restrict__ cmat) {
    __shared__ unsigned cnt[NBIN];
    int t = threadIdx.x;
    for (int j = t; j < NBIN; j += 256) cnt[j] = 0u;
    __syncthreads();
    size_t base = (size_t)blockIdx.x * CHP;
    unsigned n = (unsigned)((base + CHP <= N_EDGES) ? CHP : (N_EDGES - base));
    for (unsigned i = t; i < n; i += 256)
        atomicAdd(&cnt[(unsigned)col[base + i] >> BSHIFT], 1u);
    __syncthreads();
    for (int j = t; j < NBIN; j += 256)
        cmat[(size_t)blockIdx.x * NBIN + j] = (unsigned short)cnt[j];
}

// ---------------- per-bucket column scan over chunks -> pmat + totals ----------------
__global__ void k_colscan(const unsigned short* __restrict__ cmat,
                          unsigned short* __restrict__ pmat,
                          unsigned* __restrict__ bcnt) {
    __shared__ unsigned s0[256], s1[256];
    int j = blockIdx.x, t = threadIdx.x;
    unsigned v[CIPT];
    unsigned tot = 0;
#pragma unroll
    for (int k = 0; k < CIPT; ++k) {
        int i = t * CIPT + k;
        v[k] = (i < NCHUNK) ? (unsigned)cmat[(size_t)i * NBIN + j] : 0u;
        tot += v[k];
    }
    s0[t] = tot;
    __syncthreads();
    unsigned* src = s0;
    unsigned* dst = s1;
    for (int d = 1; d < 256; d <<= 1) {
        unsigned xv = src[t] + ((t >= d) ? src[t - d] : 0u);
        dst[t] = xv;
        __syncthreads();
        unsigned* tmp = src; src = dst; dst = tmp;
    }
    unsigned run = src[t] - tot;
#pragma unroll
    for (int k = 0; k < CIPT; ++k) {
        int i = t * CIPT + k;
        if (i < NCHUNK) pmat[(size_t)i * NBIN + j] = (unsigned short)run;
        run += v[k];
    }
    if (t == 0) bcnt[(size_t)j * 8] = src[255];
}

// ---------------- exclusive scan over NBIN totals -> boff ----------------
__global__ void k_scan2(const unsigned* __restrict__ bcnt, unsigned* __restrict__ boff) {
    __shared__ unsigned s0[1024];
    __shared__ unsigned s1[1024];
    int t = threadIdx.x;
    unsigned v = (t < NBIN) ? bcnt[(size_t)t * 8] : 0u;
    s0[t] = v;
    __syncthreads();
    unsigned* src = s0;
    unsigned* dst = s1;
    for (int d = 1; d < 1024; d <<= 1) {
        unsigned xv = src[t] + ((t >= d) ? src[t - d] : 0u);
        dst[t] = xv;
        __syncthreads();
        unsigned* tmp = src; src = dst; dst = tmp;
    }
    if (t < NBIN) boff[t] = src[t] - v;
    if (t == 0) boff[NBIN] = N_EDGES;
}

// ---------------- placement + fused weighted degree ----------------
// record: x = row(18b) | local(8b)<<18, y = weight bits
__global__ __launch_bounds__(256)
void k_place(const int* __restrict__ row, const int* __restrict__ col,
             const float* __restrict__ w,
             const unsigned short* __restrict__ cmat,
             const unsigned short* __restrict__ pmat,
             const unsigned* __restrict__ boff,
             uint2* __restrict__ edata, float* __restrict__ deg) {
    __shared__ uint2 sorted[CHP];                 // 32 KB
    __shared__ unsigned short binof[CHP];         // 8 KB
    __shared__ unsigned short excl16[NBIN];       // 1.6 KB
    __shared__ unsigned cur[NBIN];                // 3.1 KB
    __shared__ unsigned gbase[NBIN];              // 3.1 KB
    __shared__ unsigned wpre[4];
    int t = threadIdx.x;
    int lane = t & 63, wid = t >> 6;
    int chunk = blockIdx.x;
    size_t base = (size_t)chunk * CHP;
    unsigned n = (unsigned)((base + CHP <= N_EDGES) ? CHP : (N_EDGES - base));

    // load col into regs (coalesced)
    int colr[CHP / 256];
#pragma unroll
    for (int k = 0; k < CHP / 256; ++k) {
        unsigned i = (unsigned)k * 256u + (unsigned)t;
        colr[k] = (i < n) ? col[base + i] : -1;
    }
    // local bin counts from cmat row + wave scan (thread t owns bins 4t..4t+3)
    unsigned cc[4];
    unsigned tsum = 0;
#pragma unroll
    for (int j = 0; j < 4; ++j) {
        int bin = 4 * t + j;
        cc[j] = (bin < NBIN) ? (unsigned)cmat[(size_t)chunk * NBIN + bin] : 0u;
        tsum += cc[j];
    }
    unsigned v = tsum;
#pragma unroll
    for (int d = 1; d < 64; d <<= 1) {
        unsigned u = __shfl_up(v, d, 64);
        if (lane >= d) v += u;
    }
    if (lane == 63) wpre[wid] = v;
    __syncthreads();
    unsigned wp = 0;
#pragma unroll
    for (int wI = 0; wI < 4; ++wI)
        if (wI < wid) wp += wpre[wI];
    unsigned run = v + wp - tsum;   // exclusive prefix over bins
#pragma unroll
    for (int j = 0; j < 4; ++j) {
        int bin = 4 * t + j;
        if (bin < NBIN) {
            excl16[bin] = (unsigned short)run;
            cur[bin] = run;
            gbase[bin] = boff[bin] + (unsigned)pmat[(size_t)chunk * NBIN + bin];
        }
        run += cc[j];
    }
    __syncthreads();
    // scatter into sorted LDS + record bin + fused deg atomic
#pragma unroll
    for (int k = 0; k < CHP / 256; ++k) {
        unsigned i = (unsigned)k * 256u + (unsigned)t;
        if (i < n) {
            size_t e = base + i;
            int ccv = colr[k];
            unsigned b = (unsigned)ccv >> BSHIFT;
            float wv = w[e];
            atomicAdd(&deg[ccv], wv);   // fused weighted degree
            unsigned pos = atomicAdd(&cur[b], 1u);
            uint2 rec;
            rec.x = (unsigned)row[e] | (((unsigned)ccv & (BSIZE - 1)) << 18);
            rec.y = __float_as_uint(wv);
            sorted[pos] = rec;
            binof[pos] = (unsigned short)b;
        }
    }
    __syncthreads();
    // flat parallel write-out; adjacent j mostly same bin -> coalesced
    for (unsigned j = t; j < n; j += 256) {
        unsigned b = binof[j];
        edata[(size_t)gbase[b] + (j - (unsigned)excl16[b])] = sorted[j];
    }
}

// ---------------- per-channel affine from stats ----------------
__global__ void k_norm_params(const float* __restrict__ stats, const float* __restrict__ gw,
                              const float* __restrict__ gb, const float* __restrict__ gms,
                              float* __restrict__ ab, int C) {
    int c = threadIdx.x;
    if (c < C) {
        float mean = stats[c] * (1.0f / N_NODES);
        float meansq = stats[C + c] * (1.0f / N_NODES);
        float ms = gms[c];
        float var = meansq - 2.f * ms * mean * mean + ms * ms * mean * mean;
        float alpha = gw[c] * rsqrtf(var + EPS_F);
        ab[c] = alpha;
        ab[C + c] = gb[c] - alpha * ms * mean;
    }
}

// ---------------- norm1+leaky -> h = x1n @ W (9x8), hs = fp16(dinv*h) ----------------
__global__ void k_x1_to_hs(const float* __restrict__ x1_raw, const float* __restrict__ ab1,
                           const float* __restrict__ gcn_w, const float* __restrict__ deg,
                           uint4* __restrict__ hsh) {
    __shared__ float W[72];
    __shared__ float A[9], B[9];
    if (threadIdx.x < 72) W[threadIdx.x] = gcn_w[threadIdx.x];
    if (threadIdx.x < 9) { A[threadIdx.x] = ab1[threadIdx.x]; B[threadIdx.x] = ab1[9 + threadIdx.x]; }
    __syncthreads();
    int i = blockIdx.x * blockDim.x + threadIdx.x;
    if (i >= N_NODES) return;
    float v[9];
#pragma unroll
    for (int c = 0; c < 9; ++c) {
        float t = A[c] * x1_raw[(size_t)i * 9 + c] + B[c];
        v[c] = t >= 0.f ? t : NEG_SLOPE * t;
    }
    float di = rsqrtf(fmaxf(deg[i] + 1.0f, EPS_F));
    float o[8];
#pragma unroll
    for (int c = 0; c < 8; ++c) {
        float s = 0.f;
#pragma unroll
        for (int k = 0; k < 9; ++k) s += v[k] * W[k * 8 + c];
        o[c] = s * di;
    }
    uint4 pk;
    __half2 p0 = __floats2half2_rn(o[0], o[1]);
    __half2 p1 = __floats2half2_rn(o[2], o[3]);
    __half2 p2 = __floats2half2_rn(o[4], o[5]);
    __half2 p3 = __floats2half2_rn(o[6], o[7]);
    pk.x = *(unsigned*)&p0; pk.y = *(unsigned*)&p1;
    pk.z = *(unsigned*)&p2; pk.w = *(unsigned*)&p3;
    hsh[i] = pk;
}

// ---------------- 3-way split count-sort + register accumulate -> partials ----------------
__global__ __launch_bounds__(256)
void k_acc_sp(const uint2* __restrict__ edata, const unsigned* __restrict__ boff,
              const uint4* __restrict__ hsh, float* __restrict__ part) {
    __shared__ uint2 sorted[CHA];            // 24 KB
    __shared__ unsigned cnt[256];
    __shared__ unsigned wpre[4];
    int b = blockIdx.x / SACC, s = blockIdx.x % SACC;
    int t = threadIdx.x;
    int lane = t & 63, wid = t >> 6;
    float acc[8];
#pragma unroll
    for (int c = 0; c < 8; ++c) acc[c] = 0.f;
    unsigned e0 = boff[b], e1 = boff[b + 1];
    unsigned n = e1 - e0;
    unsigned a = e0 + (n * (unsigned)s) / (unsigned)SACC;
    unsigned bnd = e0 + (n * (unsigned)(s + 1)) / (unsigned)SACC;

    for (unsigned c0 = a; c0 < bnd; c0 += CHA) {
        unsigned nch = min((unsigned)CHA, bnd - c0);
        cnt[t] = 0u;
        __syncthreads();
        // single global read: records to regs + LDS hist
        uint2 rr[CHA / 256];
#pragma unroll
        for (int k = 0; k < CHA / 256; ++k) {
            unsigned i = (unsigned)k * 256u + (unsigned)t;
            if (i < nch) {
                rr[k] = edata[c0 + i];
                atomicAdd(&cnt[(rr[k].x >> 18) & 255u], 1u);
            } else {
                rr[k].x = 0xFFFFFFFFu;  // marker (valid recs have x < 2^26)
            }
        }
        __syncthreads();
        unsigned myc = cnt[t];
        // wave shfl inclusive scan + cross-wave combine
        unsigned v = myc;
#pragma unroll
        for (int d = 1; d < 64; d <<= 1) {
            unsigned u = __shfl_up(v, d, 64);
            if (lane >= d) v += u;
        }
        if (lane == 63) wpre[wid] = v;
        __syncthreads();
        unsigned wp = 0;
#pragma unroll
        for (int wI = 0; wI < 4; ++wI)
            if (wI < wid) wp += wpre[wI];
        unsigned st = v + wp - myc;  // exclusive start of col t's run
        cnt[t] = st;                 // reuse cnt as cursor
        __syncthreads();
        // scatter from regs into sorted
#pragma unroll
        for (int k = 0; k < CHA / 256; ++k) {
            if (rr[k].x != 0xFFFFFFFFu) {
                unsigned bin = (rr[k].x >> 18) & 255u;
                unsigned pos = atomicAdd(&cnt[bin], 1u);
                sorted[pos] = rr[k];
            }
        }
        __syncthreads();
        // walk col t's contiguous run [st, st+myc), 4-deep gather batching
        unsigned j = st, jend = st + myc;
        for (; j + 4 <= jend; j += 4) {
            uint2 r0 = sorted[j], r1 = sorted[j + 1], r2 = sorted[j + 2], r3 = sorted[j + 3];
            uint4 h0 = hsh[r0.x & 0x3FFFFu];
            uint4 h1 = hsh[r1.x & 0x3FFFFu];
            uint4 h2 = hsh[r2.x & 0x3FFFFu];
            uint4 h3 = hsh[r3.x & 0x3FFFFu];
            float w0 = __uint_as_float(r0.y), w1 = __uint_as_float(r1.y);
            float w2 = __uint_as_float(r2.y), w3 = __uint_as_float(r3.y);
            float f0[8], f1[8], f2[8], f3[8];
            unpack_h8(h0, f0);
            unpack_h8(h1, f1);
            unpack_h8(h2, f2);
            unpack_h8(h3, f3);
#pragma unroll
            for (int c = 0; c < 8; ++c)
                acc[c] += w0 * f0[c] + w1 * f1[c] + w2 * f2[c] + w3 * f3[c];
        }
        for (; j < jend; ++j) {
            uint2 r0 = sorted[j];
            uint4 h0 = hsh[r0.x & 0x3FFFFu];
            float w0 = __uint_as_float(r0.y);
            float f0[8];
            unpack_h8(h0, f0);
#pragma unroll
            for (int c = 0; c < 8; ++c) acc[c] += w0 * f0[c];
        }
        __syncthreads();
    }
    // write partial (coalesced)
    size_t pb = (size_t)blockIdx.x * (8 * 256);
#pragma unroll
    for (int c = 0; c < 8; ++c) part[pb + (size_t)c * 256 + t] = acc[c];
}

// ---------------- combine SACC partials + self loop -> x2, stats2 ----------------
__global__ void k_combine2(const float* __restrict__ part, const uint4* __restrict__ hsh,
                           const float* __restrict__ deg, const float* __restrict__ gcn_b,
                           float* __restrict__ x2, float* __restrict__ stats2) {
    __shared__ float sst[16];
    int b = blockIdx.x, t = threadIdx.x;
    if (t < 16) sst[t] = 0.f;
    __syncthreads();
    int node = (b << BSHIFT) + t;
    float ls[8], lq[8];
#pragma unroll
    for (int c = 0; c < 8; ++c) { ls[c] = 0.f; lq[c] = 0.f; }
    if (node < N_NODES) {
        size_t pb = (size_t)b * SACC * (8 * 256);
        float a[8];
#pragma unroll
        for (int c = 0; c < 8; ++c) {
            float sv = 0.f;
#pragma unroll
            for (int sp = 0; sp < SACC; ++sp)
                sv += part[pb + (size_t)sp * (8 * 256) + (size_t)c * 256 + t];
            a[c] = sv;
        }
        float di = rsqrtf(fmaxf(deg[node] + 1.0f, EPS_F));
        float self[8];
        unpack_h8(hsh[node], self);
        float o[8];
#pragma unroll
        for (int c = 0; c < 8; ++c) {
            float vv = di * (a[c] + self[c]) + gcn_b[c];
            o[c] = vv;
            ls[c] = vv;
            lq[c] = vv * vv;
        }
        float4* xp = (float4*)(x2 + (size_t)node * 8);
        xp[0] = make_float4(o[0], o[1], o[2], o[3]);
        xp[1] = make_float4(o[4], o[5], o[6], o[7]);
    }
#pragma unroll
    for (int c = 0; c < 8; ++c) {
        float sv = ls[c], qv = lq[c];
#pragma unroll
        for (int off = 32; off > 0; off >>= 1) {
            sv += __shfl_down(sv, off, 64);
            qv += __shfl_down(qv, off, 64);
        }
        if ((t & 63) == 0) { atomicAdd(&sst[c], sv); atomicAdd(&sst[8 + c], qv); }
    }
    __syncthreads();
    if (t < 16) atomicAdd(&stats2[t], sst[t]);
}

// ---------------- out = leaky(norm2(x2)) . fc_w + fc_b ----------------
__global__ void k_out(const float* __restrict__ x2, const float* __restrict__ ab2,
                      const float* __restrict__ fc_w, const float* __restrict__ fc_b,
                      float* __restrict__ out) {
    int i = blockIdx.x * blockDim.x + threadIdx.x;
    if (i >= N_NODES) return;
    const float4* xp = (const float4*)(x2 + (size_t)i * 8);
    float4 a = xp[0], b4 = xp[1];
    float v[8] = {a.x, a.y, a.z, a.w, b4.x, b4.y, b4.z, b4.w};
    float s = fc_b[0];
#pragma unroll
    for (int c = 0; c < 8; ++c) {
        float t = ab2[c] * v[c] + ab2[8 + c];
        t = t >= 0.f ? t : NEG_SLOPE * t;
        s += t * fc_w[c];
    }
    out[i] = s;
}

// =================== tier3 (small-ws) path: atomic scatter, fp16 hs ===================
__global__ void f_deg(const int* __restrict__ col, const float* __restrict__ w,
                      float* __restrict__ deg) {
    int e = blockIdx.x * blockDim.x + threadIdx.x;
    if (e < N_EDGES) atomicAdd(&deg[col[e]], w[e]);
}
__global__ void f_init_acc(const uint4* __restrict__ hsh, float* __restrict__ acc) {
    int i = blockIdx.x * blockDim.x + threadIdx.x;
    if (i >= N_NODES) return;
    float f[8];
    unpack_h8(hsh[i], f);
#pragma unroll
    for (int c = 0; c < 8; ++c) acc[(size_t)i * 8 + c] = f[c];
}
__global__ void f_scatter(const int* __restrict__ row, const int* __restrict__ col,
                          const float* __restrict__ ew, const uint4* __restrict__ hsh,
                          float* __restrict__ acc) {
    int e = blockIdx.x * blockDim.x + threadIdx.x;
    if (e >= N_EDGES) return;
    int r = row[e], c = col[e];
    float w = ew[e];
    float f[8];
    unpack_h8(hsh[r], f);
    float* ap = acc + (size_t)c * 8;
#pragma unroll
    for (int k = 0; k < 8; ++k) atomicAdd(ap + k, w * f[k]);
}
__global__ void f_x2_stats(const float* __restrict__ acc, const float* __restrict__ deg,
                           const float* __restrict__ gcn_b, float* __restrict__ x2,
                           float* __restrict__ stats2) {
    int i = blockIdx.x * blockDim.x + threadIdx.x;
    float vals[8];
    if (i < N_NODES) {
        float di = rsqrtf(fmaxf(deg[i] + 1.0f, EPS_F));
#pragma unroll
        for (int c = 0; c < 8; ++c) {
            float t = di * acc[(size_t)i * 8 + c] + gcn_b[c];
            vals[c] = t;
            x2[(size_t)i * 8 + c] = t;
        }
    } else {
#pragma unroll
        for (int c = 0; c < 8; ++c) vals[c] = 0.f;
    }
    __shared__ float sh[16];
    if (threadIdx.x < 16) sh[threadIdx.x] = 0.f;
    __syncthreads();
#pragma unroll
    for (int c = 0; c < 8; ++c) {
        float s = vals[c], q = vals[c] * vals[c];
#pragma unroll
        for (int off = 32; off > 0; off >>= 1) {
            s += __shfl_down(s, off, 64);
            q += __shfl_down(q, off, 64);
        }
        if ((threadIdx.x & 63) == 0) { atomicAdd(&sh[c], s); atomicAdd(&sh[8 + c], q); }
    }
    __syncthreads();
    if (threadIdx.x < 16) atomicAdd(&stats2[threadIdx.x], sh[threadIdx.x]);
}

extern "C" void kernel_launch(void* const* d_in, const int* in_sizes, int n_in,
                              void* d_out, int out_size, void* d_ws, size_t ws_size,
                              hipStream_t stream) {
    const float* x = (const float*)d_in[0];
    const int* edge_index = (const int*)d_in[1];
    const float* edge_weight = (const float*)d_in[2];
    const float* gru_w_ih = (const float*)d_in[3];
    const float* gru_w_hh = (const float*)d_in[4];
    const float* gru_b_ih = (const float*)d_in[5];
    const float* gru_b_hh = (const float*)d_in[6];
    const float* gn1_w = (const float*)d_in[7];
    const float* gn1_b = (const float*)d_in[8];
    const float* gn1_ms = (const float*)d_in[9];
    const float* gn2_w = (const float*)d_in[10];
    const float* gn2_b = (const float*)d_in[11];
    const float* gn2_ms = (const float*)d_in[12];
    const float* gcn_w = (const float*)d_in[13];
    const float* gcn_b = (const float*)d_in[14];
    const float* fc_w = (const float*)d_in[15];
    const float* fc_b = (const float*)d_in[16];
    float* out = (float*)d_out;

    const int* e_row = edge_index;
    const int* e_col = edge_index + N_EDGES;

    float* ws = (float*)d_ws;
    const size_t N = N_NODES;
    const int BT = 256;
    const int nblk = (N_NODES + BT - 1) / BT;

    // layout (words): stats1[0..18) stats2[18..34) ab1[34..52) ab2[52..68)
    // bcnt_pad[68 .. +NBIN*8) boff[.. +NBIN+1), align4,
    // cmat u16[NCHUNK*NBIN], pmat u16[NCHUNK*NBIN], align4,
    // deg[N], x1_raw[9N] (reused as x2), hsh[4N words], edata[2E words], part[NBKT*SACC*2048]
    const size_t HOFF_BCNT = 68;
    const size_t HOFF_BOFF = HOFF_BCNT + (size_t)NBIN * 8;
    size_t off = HOFF_BOFF + NBIN + 1;
    off = (off + 3) & ~(size_t)3;
    const size_t CMW = ((size_t)NCHUNK * NBIN + 1) / 2;   // u16 pairs -> words
    const size_t OFF_CMAT = off;  off += CMW;
    off = (off + 3) & ~(size_t)3;
    const size_t OFF_PMAT = off;  off += CMW;
    off = (off + 3) & ~(size_t)3;
    const size_t OFF_DEG = off;
    const size_t OFF_X1 = OFF_DEG + N;
    const size_t OFF_HS = (OFF_X1 + 9 * N + 3) & ~(size_t)3;   // uint4-aligned
    const size_t OFF_ED = OFF_HS + 4 * N;
    const size_t OFF_PART = OFF_ED + (size_t)N_EDGES * 2;
    const size_t need1 = (OFF_PART + (size_t)NBKT * SACC * 8 * 256) * 4;

    float* stats1 = ws;
    float* stats2 = ws + 18;
    float* ab1 = ws + 34;
    float* ab2 = ws + 52;

    if (ws_size >= need1) {
        unsigned* bcnt = (unsigned*)(ws + HOFF_BCNT);
        unsigned* boff = (unsigned*)(ws + HOFF_BOFF);
        unsigned short* cmat = (unsigned short*)(ws + OFF_CMAT);
        unsigned short* pmat = (unsigned short*)(ws + OFF_PMAT);
        float* deg = ws + OFF_DEG;
        float* x1_raw = ws + OFF_X1;
        uint4* hsh = (uint4*)(ws + OFF_HS);
        uint2* edata = (uint2*)(ws + OFF_ED);
        float* part = ws + OFF_PART;
        float* x2 = x1_raw;  // x1_raw dead after k_x1_to_hs

        hipMemsetAsync(ws, 0, 68 * sizeof(float), stream);   // stats+ab only
        hipMemsetAsync(deg, 0, N * sizeof(float), stream);

        k_gru<<<nblk, BT, 0, stream>>>(x, gru_w_ih, gru_w_hh, gru_b_ih, gru_b_hh, x1_raw, stats1);
        k_hist2<<<NCHUNK, BT, 0, stream>>>(e_col, cmat);
        k_colscan<<<NBIN, BT, 0, stream>>>(cmat, pmat, bcnt);
        k_scan2<<<1, 1024, 0, stream>>>(bcnt, boff);
        k_place<<<NCHUNK, BT, 0, stream>>>(e_row, e_col, edge_weight, cmat, pmat, boff, edata, deg);
        k_norm_params<<<1, 32, 0, stream>>>(stats1, gn1_w, gn1_b, gn1_ms, ab1, 9);
        k_x1_to_hs<<<nblk, BT, 0, stream>>>(x1_raw, ab1, gcn_w, deg, hsh);
        k_acc_sp<<<NBKT * SACC, BT, 0, stream>>>(edata, boff, hsh, part);
        k_combine2<<<NBKT, BT, 0, stream>>>(part, hsh, deg, gcn_b, x2, stats2);
        k_norm_params<<<1, 32, 0, stream>>>(stats2, gn2_w, gn2_b, gn2_ms, ab2, 8);
        k_out<<<nblk, BT, 0, stream>>>(x2, ab2, fc_w, fc_b, out);
    } else {
        // tier3: atomic scatter (needs ~22.5N floats)
        float* deg = ws + 68;
        float* x1_raw = deg + N;
        size_t hsoff = (size_t)(68 + N + 9 * N);
        hsoff = (hsoff + 3) & ~(size_t)3;
        uint4* hsh = (uint4*)(ws + hsoff);
        float* acc = ws + hsoff + 4 * N;
        float* x2 = x1_raw;

        hipMemsetAsync(ws, 0, (68 + N) * sizeof(float), stream);

        const int eblk = (N_EDGES + BT - 1) / BT;
        k_gru<<<nblk, BT, 0, stream>>>(x, gru_w_ih, gru_w_hh, gru_b_ih, gru_b_hh, x1_raw, stats1);
        f_deg<<<eblk, BT, 0, stream>>>(e_col, edge_weight, deg);
        k_norm_params<<<1, 32, 0, stream>>>(stats1, gn1_w, gn1_b, gn1_ms, ab1, 9);
        k_x1_to_hs<<<nblk, BT, 0, stream>>>(x1_raw, ab1, gcn_w, deg, hsh);
        f_init_acc<<<nblk, BT, 0, stream>>>(hsh, acc);
        f_scatter<<<eblk, BT, 0, stream>>>(e_row, e_col, edge_weight, hsh, acc);
        f_x2_stats<<<nblk, BT, 0, stream>>>(acc, deg, gcn_b, x2, stats2);
        k_norm_params<<<1, 32, 0, stream>>>(stats2, gn2_w, gn2_b, gn2_ms, ab2, 8);
        k_out<<<nblk, BT, 0, stream>>>(x2, ab2, fc_w, fc_b, out);
    }
}

// Round 15
// 216.854 us; speedup vs baseline: 2.1344x; 2.1344x over previous
//
#include <hip/hip_runtime.h>
#include <hip/hip_fp16.h>
#include <math.h>

#define N_NODES 200000
#define N_EDGES 6400000
#define NEG_SLOPE 0.01f
#define EPS_F 1e-5f

// bucket partition params
#define BSHIFT 8
#define BSIZE 256                      // nodes per bucket
#define NBKT 782                       // ceil(N_NODES / 256)
#define NBIN 784                       // padded bin count
#define CHP 4096                       // edges per place chunk (r12 proven)
#define NCHUNK ((N_EDGES + CHP - 1) / CHP)   // 1563
#define CIPT 7                         // colscan chunks per thread (256*7 >= 1563)

// k_acc_sp params
#define SACC 3                         // splits per bucket
#define CHA 3072                       // edges per sort pass (24 KB)

__device__ __forceinline__ float sigmoidf_(float x) { return 1.0f / (1.0f + expf(-x)); }

__device__ __forceinline__ void unpack_h8(uint4 hv, float* f) {
    __half2* hp = (__half2*)&hv;
    float2 f0 = __half22float2(hp[0]);
    float2 f1 = __half22float2(hp[1]);
    float2 f2 = __half22float2(hp[2]);
    float2 f3 = __half22float2(hp[3]);
    f[0] = f0.x; f[1] = f0.y; f[2] = f1.x; f[3] = f1.y;
    f[4] = f2.x; f[5] = f2.y; f[6] = f3.x; f[7] = f3.y;
}

// ---------------- K1: per-node GRU + x1_raw + stats1 ----------------
__global__ void k_gru(const float* __restrict__ x,
                      const float* __restrict__ w_ih, const float* __restrict__ w_hh,
                      const float* __restrict__ b_ih, const float* __restrict__ b_hh,
                      float* __restrict__ x1_raw, float* __restrict__ stats1) {
    __shared__ float xs[5 * 256];
    int base = blockIdx.x * (5 * 256);
    for (int j = threadIdx.x; j < 5 * 256; j += 256) {
        int g = base + j;
        if (g < 5 * N_NODES) xs[j] = x[g];
    }
    __syncthreads();
    int i = blockIdx.x * blockDim.x + threadIdx.x;
    float vals[9];
    if (i < N_NODES) {
        float xv[5];
#pragma unroll
        for (int j = 0; j < 5; ++j) xv[j] = xs[threadIdx.x * 5 + j];
        float wih[6], whh[12], bih[6], bhh[6];
#pragma unroll
        for (int j = 0; j < 6; ++j) { wih[j] = w_ih[j]; bih[j] = b_ih[j]; bhh[j] = b_hh[j]; }
#pragma unroll
        for (int j = 0; j < 12; ++j) whh[j] = w_hh[j];
        float h0 = 0.f, h1 = 0.f;
#pragma unroll
        for (int t = 0; t < 4; ++t) {
            float xt = xv[t];
            float gi[6], gh[6];
#pragma unroll
            for (int j = 0; j < 6; ++j) {
                gi[j] = xt * wih[j] + bih[j];
                gh[j] = h0 * whh[2 * j] + h1 * whh[2 * j + 1] + bhh[j];
            }
            float r0 = sigmoidf_(gi[0] + gh[0]);
            float r1 = sigmoidf_(gi[1] + gh[1]);
            float z0 = sigmoidf_(gi[2] + gh[2]);
            float z1 = sigmoidf_(gi[3] + gh[3]);
            float n0 = tanhf(gi[4] + r0 * gh[4]);
            float n1 = tanhf(gi[5] + r1 * gh[5]);
            h0 = (1.f - z0) * n0 + z0 * h0;
            h1 = (1.f - z1) * n1 + z1 * h1;
            vals[2 * t] = h0;
            vals[2 * t + 1] = h1;
        }
        vals[8] = xv[4];
#pragma unroll
        for (int c = 0; c < 9; ++c) x1_raw[(size_t)i * 9 + c] = vals[c];
    } else {
#pragma unroll
        for (int c = 0; c < 9; ++c) vals[c] = 0.f;
    }
    __shared__ float sh[18];
    __syncthreads();
    if (threadIdx.x < 18) sh[threadIdx.x] = 0.f;
    __syncthreads();
#pragma unroll
    for (int c = 0; c < 9; ++c) {
        float s = vals[c], q = vals[c] * vals[c];
#pragma unroll
        for (int off = 32; off > 0; off >>= 1) {
            s += __shfl_down(s, off, 64);
            q += __shfl_down(q, off, 64);
        }
        if ((threadIdx.x & 63) == 0) { atomicAdd(&sh[c], s); atomicAdd(&sh[9 + c], q); }
    }
    __syncthreads();
    if (threadIdx.x < 18) atomicAdd(&stats1[threadIdx.x], sh[threadIdx.x]);
}

// ---------------- per-chunk histogram -> cmat (no global atomics) ----------------
__global__ void k_hist2(const int* __restrict__ col, unsigned short* __restrict__ cmat) {
    __shared__ unsigned cnt[NBIN];
    int t = threadIdx.x;
    for (int j = t; j < NBIN; j += 256) cnt[j] = 0u;
    __syncthreads();
    size_t base = (size_t)blockIdx.x * CHP;
    unsigned n = (unsigned)((base + CHP <= N_EDGES) ? CHP : (N_EDGES - base));
    for (unsigned i = t; i < n; i += 256)
        atomicAdd(&cnt[(unsigned)col[base + i] >> BSHIFT], 1u);
    __syncthreads();
    for (int j = t; j < NBIN; j += 256)
        cmat[(size_t)blockIdx.x * NBIN + j] = (unsigned short)cnt[j];
}

// ---------------- per-bucket column scan over chunks -> pmat + totals ----------------
__global__ void k_colscan(const unsigned short* __restrict__ cmat,
                          unsigned short* __restrict__ pmat,
                          unsigned* __restrict__ bcnt) {
    __shared__ unsigned s0[256], s1[256];
    int j = blockIdx.x, t = threadIdx.x;
    unsigned v[CIPT];
    unsigned tot = 0;
#pragma unroll
    for (int k = 0; k < CIPT; ++k) {
        int i = t * CIPT + k;
        v[k] = (i < NCHUNK) ? (unsigned)cmat[(size_t)i * NBIN + j] : 0u;
        tot += v[k];
    }
    s0[t] = tot;
    __syncthreads();
    unsigned* src = s0;
    unsigned* dst = s1;
    for (int d = 1; d < 256; d <<= 1) {
        unsigned xv = src[t] + ((t >= d) ? src[t - d] : 0u);
        dst[t] = xv;
        __syncthreads();
        unsigned* tmp = src; src = dst; dst = tmp;
    }
    unsigned run = src[t] - tot;
#pragma unroll
    for (int k = 0; k < CIPT; ++k) {
        int i = t * CIPT + k;
        if (i < NCHUNK) pmat[(size_t)i * NBIN + j] = (unsigned short)run;
        run += v[k];
    }
    if (t == 0) bcnt[(size_t)j * 8] = src[255];
}

// ---------------- exclusive scan over NBIN totals -> boff ----------------
__global__ void k_scan2(const unsigned* __restrict__ bcnt, unsigned* __restrict__ boff) {
    __shared__ unsigned s0[1024];
    __shared__ unsigned s1[1024];
    int t = threadIdx.x;
    unsigned v = (t < NBIN) ? bcnt[(size_t)t * 8] : 0u;
    s0[t] = v;
    __syncthreads();
    unsigned* src = s0;
    unsigned* dst = s1;
    for (int d = 1; d < 1024; d <<= 1) {
        unsigned xv = src[t] + ((t >= d) ? src[t - d] : 0u);
        dst[t] = xv;
        __syncthreads();
        unsigned* tmp = src; src = dst; dst = tmp;
    }
    if (t < NBIN) boff[t] = src[t] - v;
    if (t == 0) boff[NBIN] = N_EDGES;
}

// ---------------- placement: deterministic offsets, zero global atomics ----------------
// record: x = row(18b) | local(8b)<<18, y = weight bits
__global__ __launch_bounds__(256)
void k_place(const int* __restrict__ row, const int* __restrict__ col,
             const float* __restrict__ w,
             const unsigned short* __restrict__ cmat,
             const unsigned short* __restrict__ pmat,
             const unsigned* __restrict__ boff,
             uint2* __restrict__ edata) {
    __shared__ uint2 sorted[CHP];                 // 32 KB
    __shared__ unsigned short binof[CHP];         // 8 KB
    __shared__ unsigned short excl16[NBIN];       // 1.6 KB
    __shared__ unsigned cur[NBIN];                // 3.1 KB
    __shared__ unsigned gbase[NBIN];              // 3.1 KB
    __shared__ unsigned wpre[4];
    int t = threadIdx.x;
    int lane = t & 63, wid = t >> 6;
    int chunk = blockIdx.x;
    size_t base = (size_t)chunk * CHP;
    unsigned n = (unsigned)((base + CHP <= N_EDGES) ? CHP : (N_EDGES - base));

    // load col into regs (coalesced)
    int colr[CHP / 256];
#pragma unroll
    for (int k = 0; k < CHP / 256; ++k) {
        unsigned i = (unsigned)k * 256u + (unsigned)t;
        colr[k] = (i < n) ? col[base + i] : -1;
    }
    // local bin counts from cmat row + wave scan (thread t owns bins 4t..4t+3)
    unsigned cc[4];
    unsigned tsum = 0;
#pragma unroll
    for (int j = 0; j < 4; ++j) {
        int bin = 4 * t + j;
        cc[j] = (bin < NBIN) ? (unsigned)cmat[(size_t)chunk * NBIN + bin] : 0u;
        tsum += cc[j];
    }
    unsigned v = tsum;
#pragma unroll
    for (int d = 1; d < 64; d <<= 1) {
        unsigned u = __shfl_up(v, d, 64);
        if (lane >= d) v += u;
    }
    if (lane == 63) wpre[wid] = v;
    __syncthreads();
    unsigned wp = 0;
#pragma unroll
    for (int wI = 0; wI < 4; ++wI)
        if (wI < wid) wp += wpre[wI];
    unsigned run = v + wp - tsum;   // exclusive prefix over bins
#pragma unroll
    for (int j = 0; j < 4; ++j) {
        int bin = 4 * t + j;
        if (bin < NBIN) {
            excl16[bin] = (unsigned short)run;
            cur[bin] = run;
            gbase[bin] = boff[bin] + (unsigned)pmat[(size_t)chunk * NBIN + bin];
        }
        run += cc[j];
    }
    __syncthreads();
    // scatter into sorted LDS + record bin
#pragma unroll
    for (int k = 0; k < CHP / 256; ++k) {
        unsigned i = (unsigned)k * 256u + (unsigned)t;
        if (i < n) {
            size_t e = base + i;
            int ccv = colr[k];
            unsigned b = (unsigned)ccv >> BSHIFT;
            unsigned pos = atomicAdd(&cur[b], 1u);
            uint2 rec;
            rec.x = (unsigned)row[e] | (((unsigned)ccv & (BSIZE - 1)) << 18);
            rec.y = __float_as_uint(w[e]);
            sorted[pos] = rec;
            binof[pos] = (unsigned short)b;
        }
    }
    __syncthreads();
    // flat parallel write-out; adjacent j mostly same bin -> coalesced
    for (unsigned j = t; j < n; j += 256) {
        unsigned b = binof[j];
        edata[(size_t)gbase[b] + (j - (unsigned)excl16[b])] = sorted[j];
    }
}

// ---------------- per-bucket weighted degree (4-way split, 4-edge batched) ----------------
__global__ void k_deg_split(const uint2* __restrict__ edata, const unsigned* __restrict__ boff,
                            float* __restrict__ deg) {
    __shared__ float dw[BSIZE];
    int b = blockIdx.x >> 2;
    int s = blockIdx.x & 3;
    if (threadIdx.x < BSIZE) dw[threadIdx.x] = 0.f;
    __syncthreads();
    unsigned e0 = boff[b], e1 = boff[b + 1];
    unsigned n = e1 - e0;
    unsigned a = e0 + (n * (unsigned)s) / 4u;
    unsigned bnd = e0 + (n * (unsigned)(s + 1)) / 4u;
    for (unsigned base = a + threadIdx.x; base < bnd; base += 1024) {
        uint2 d[4];
#pragma unroll
        for (int k = 0; k < 4; ++k) {
            unsigned e = base + (unsigned)k * 256u;
            d[k] = (e < bnd) ? edata[e] : make_uint2(0u, 0u);
        }
#pragma unroll
        for (int k = 0; k < 4; ++k)
            atomicAdd(&dw[(d[k].x >> 18) & (BSIZE - 1)], __uint_as_float(d[k].y));
    }
    __syncthreads();
    int node = (b << BSHIFT) + threadIdx.x;
    if (threadIdx.x < BSIZE && node < N_NODES) {
        float v = dw[threadIdx.x];
        if (v != 0.f) atomicAdd(&deg[node], v);
    }
}

// ---------------- per-channel affine from stats ----------------
__global__ void k_norm_params(const float* __restrict__ stats, const float* __restrict__ gw,
                              const float* __restrict__ gb, const float* __restrict__ gms,
                              float* __restrict__ ab, int C) {
    int c = threadIdx.x;
    if (c < C) {
        float mean = stats[c] * (1.0f / N_NODES);
        float meansq = stats[C + c] * (1.0f / N_NODES);
        float ms = gms[c];
        float var = meansq - 2.f * ms * mean * mean + ms * ms * mean * mean;
        float alpha = gw[c] * rsqrtf(var + EPS_F);
        ab[c] = alpha;
        ab[C + c] = gb[c] - alpha * ms * mean;
    }
}

// ---------------- norm1+leaky -> h = x1n @ W (9x8), hs = fp16(dinv*h) ----------------
__global__ void k_x1_to_hs(const float* __restrict__ x1_raw, const float* __restrict__ ab1,
                           const float* __restrict__ gcn_w, const float* __restrict__ deg,
                           uint4* __restrict__ hsh) {
    __shared__ float W[72];
    __shared__ float A[9], B[9];
    if (threadIdx.x < 72) W[threadIdx.x] = gcn_w[threadIdx.x];
    if (threadIdx.x < 9) { A[threadIdx.x] = ab1[threadIdx.x]; B[threadIdx.x] = ab1[9 + threadIdx.x]; }
    __syncthreads();
    int i = blockIdx.x * blockDim.x + threadIdx.x;
    if (i >= N_NODES) return;
    float v[9];
#pragma unroll
    for (int c = 0; c < 9; ++c) {
        float t = A[c] * x1_raw[(size_t)i * 9 + c] + B[c];
        v[c] = t >= 0.f ? t : NEG_SLOPE * t;
    }
    float di = rsqrtf(fmaxf(deg[i] + 1.0f, EPS_F));
    float o[8];
#pragma unroll
    for (int c = 0; c < 8; ++c) {
        float s = 0.f;
#pragma unroll
        for (int k = 0; k < 9; ++k) s += v[k] * W[k * 8 + c];
        o[c] = s * di;
    }
    uint4 pk;
    __half2 p0 = __floats2half2_rn(o[0], o[1]);
    __half2 p1 = __floats2half2_rn(o[2], o[3]);
    __half2 p2 = __floats2half2_rn(o[4], o[5]);
    __half2 p3 = __floats2half2_rn(o[6], o[7]);
    pk.x = *(unsigned*)&p0; pk.y = *(unsigned*)&p1;
    pk.z = *(unsigned*)&p2; pk.w = *(unsigned*)&p3;
    hsh[i] = pk;
}

// ---------------- 3-way split count-sort + register accumulate -> partials ----------------
__global__ __launch_bounds__(256)
void k_acc_sp(const uint2* __restrict__ edata, const unsigned* __restrict__ boff,
              const uint4* __restrict__ hsh, float* __restrict__ part) {
    __shared__ uint2 sorted[CHA];            // 24 KB
    __shared__ unsigned cnt[256];
    __shared__ unsigned wpre[4];
    int b = blockIdx.x / SACC, s = blockIdx.x % SACC;
    int t = threadIdx.x;
    int lane = t & 63, wid = t >> 6;
    float acc[8];
#pragma unroll
    for (int c = 0; c < 8; ++c) acc[c] = 0.f;
    unsigned e0 = boff[b], e1 = boff[b + 1];
    unsigned n = e1 - e0;
    unsigned a = e0 + (n * (unsigned)s) / (unsigned)SACC;
    unsigned bnd = e0 + (n * (unsigned)(s + 1)) / (unsigned)SACC;

    for (unsigned c0 = a; c0 < bnd; c0 += CHA) {
        unsigned nch = min((unsigned)CHA, bnd - c0);
        cnt[t] = 0u;
        __syncthreads();
        // single global read: records to regs + LDS hist
        uint2 rr[CHA / 256];
#pragma unroll
        for (int k = 0; k < CHA / 256; ++k) {
            unsigned i = (unsigned)k * 256u + (unsigned)t;
            if (i < nch) {
                rr[k] = edata[c0 + i];
                atomicAdd(&cnt[(rr[k].x >> 18) & 255u], 1u);
            } else {
                rr[k].x = 0xFFFFFFFFu;  // marker (valid recs have x < 2^26)
            }
        }
        __syncthreads();
        unsigned myc = cnt[t];
        // wave shfl inclusive scan + cross-wave combine
        unsigned v = myc;
#pragma unroll
        for (int d = 1; d < 64; d <<= 1) {
            unsigned u = __shfl_up(v, d, 64);
            if (lane >= d) v += u;
        }
        if (lane == 63) wpre[wid] = v;
        __syncthreads();
        unsigned wp = 0;
#pragma unroll
        for (int wI = 0; wI < 4; ++wI)
            if (wI < wid) wp += wpre[wI];
        unsigned st = v + wp - myc;  // exclusive start of col t's run
        cnt[t] = st;                 // reuse cnt as cursor
        __syncthreads();
        // scatter from regs into sorted
#pragma unroll
        for (int k = 0; k < CHA / 256; ++k) {
            if (rr[k].x != 0xFFFFFFFFu) {
                unsigned bin = (rr[k].x >> 18) & 255u;
                unsigned pos = atomicAdd(&cnt[bin], 1u);
                sorted[pos] = rr[k];
            }
        }
        __syncthreads();
        // walk col t's contiguous run [st, st+myc), 4-deep gather batching
        unsigned j = st, jend = st + myc;
        for (; j + 4 <= jend; j += 4) {
            uint2 r0 = sorted[j], r1 = sorted[j + 1], r2 = sorted[j + 2], r3 = sorted[j + 3];
            uint4 h0 = hsh[r0.x & 0x3FFFFu];
            uint4 h1 = hsh[r1.x & 0x3FFFFu];
            uint4 h2 = hsh[r2.x & 0x3FFFFu];
            uint4 h3 = hsh[r3.x & 0x3FFFFu];
            float w0 = __uint_as_float(r0.y), w1 = __uint_as_float(r1.y);
            float w2 = __uint_as_float(r2.y), w3 = __uint_as_float(r3.y);
            float f0[8], f1[8], f2[8], f3[8];
            unpack_h8(h0, f0);
            unpack_h8(h1, f1);
            unpack_h8(h2, f2);
            unpack_h8(h3, f3);
#pragma unroll
            for (int c = 0; c < 8; ++c)
                acc[c] += w0 * f0[c] + w1 * f1[c] + w2 * f2[c] + w3 * f3[c];
        }
        for (; j < jend; ++j) {
            uint2 r0 = sorted[j];
            uint4 h0 = hsh[r0.x & 0x3FFFFu];
            float w0 = __uint_as_float(r0.y);
            float f0[8];
            unpack_h8(h0, f0);
#pragma unroll
            for (int c = 0; c < 8; ++c) acc[c] += w0 * f0[c];
        }
        __syncthreads();
    }
    // write partial (coalesced)
    size_t pb = (size_t)blockIdx.x * (8 * 256);
#pragma unroll
    for (int c = 0; c < 8; ++c) part[pb + (size_t)c * 256 + t] = acc[c];
}

// ---------------- combine SACC partials + self loop -> x2, stats2 ----------------
__global__ void k_combine2(const float* __restrict__ part, const uint4* __restrict__ hsh,
                           const float* __restrict__ deg, const float* __restrict__ gcn_b,
                           float* __restrict__ x2, float* __restrict__ stats2) {
    __shared__ float sst[16];
    int b = blockIdx.x, t = threadIdx.x;
    if (t < 16) sst[t] = 0.f;
    __syncthreads();
    int node = (b << BSHIFT) + t;
    float ls[8], lq[8];
#pragma unroll
    for (int c = 0; c < 8; ++c) { ls[c] = 0.f; lq[c] = 0.f; }
    if (node < N_NODES) {
        size_t pb = (size_t)b * SACC * (8 * 256);
        float a[8];
#pragma unroll
        for (int c = 0; c < 8; ++c) {
            float sv = 0.f;
#pragma unroll
            for (int sp = 0; sp < SACC; ++sp)
                sv += part[pb + (size_t)sp * (8 * 256) + (size_t)c * 256 + t];
            a[c] = sv;
        }
        float di = rsqrtf(fmaxf(deg[node] + 1.0f, EPS_F));
        float self[8];
        unpack_h8(hsh[node], self);
        float o[8];
#pragma unroll
        for (int c = 0; c < 8; ++c) {
            float vv = di * (a[c] + self[c]) + gcn_b[c];
            o[c] = vv;
            ls[c] = vv;
            lq[c] = vv * vv;
        }
        float4* xp = (float4*)(x2 + (size_t)node * 8);
        xp[0] = make_float4(o[0], o[1], o[2], o[3]);
        xp[1] = make_float4(o[4], o[5], o[6], o[7]);
    }
#pragma unroll
    for (int c = 0; c < 8; ++c) {
        float sv = ls[c], qv = lq[c];
#pragma unroll
        for (int off = 32; off > 0; off >>= 1) {
            sv += __shfl_down(sv, off, 64);
            qv += __shfl_down(qv, off, 64);
        }
        if ((t & 63) == 0) { atomicAdd(&sst[c], sv); atomicAdd(&sst[8 + c], qv); }
    }
    __syncthreads();
    if (t < 16) atomicAdd(&stats2[t], sst[t]);
}

// ---------------- out = leaky(norm2(x2)) . fc_w + fc_b ----------------
__global__ void k_out(const float* __restrict__ x2, const float* __restrict__ ab2,
                      const float* __restrict__ fc_w, const float* __restrict__ fc_b,
                      float* __restrict__ out) {
    int i = blockIdx.x * blockDim.x + threadIdx.x;
    if (i >= N_NODES) return;
    const float4* xp = (const float4*)(x2 + (size_t)i * 8);
    float4 a = xp[0], b4 = xp[1];
    float v[8] = {a.x, a.y, a.z, a.w, b4.x, b4.y, b4.z, b4.w};
    float s = fc_b[0];
#pragma unroll
    for (int c = 0; c < 8; ++c) {
        float t = ab2[c] * v[c] + ab2[8 + c];
        t = t >= 0.f ? t : NEG_SLOPE * t;
        s += t * fc_w[c];
    }
    out[i] = s;
}

// =================== tier3 (small-ws) path: atomic scatter, fp16 hs ===================
__global__ void f_deg(const int* __restrict__ col, const float* __restrict__ w,
                      float* __restrict__ deg) {
    int e = blockIdx.x * blockDim.x + threadIdx.x;
    if (e < N_EDGES) atomicAdd(&deg[col[e]], w[e]);
}
__global__ void f_init_acc(const uint4* __restrict__ hsh, float* __restrict__ acc) {
    int i = blockIdx.x * blockDim.x + threadIdx.x;
    if (i >= N_NODES) return;
    float f[8];
    unpack_h8(hsh[i], f);
#pragma unroll
    for (int c = 0; c < 8; ++c) acc[(size_t)i * 8 + c] = f[c];
}
__global__ void f_scatter(const int* __restrict__ row, const int* __restrict__ col,
                          const float* __restrict__ ew, const uint4* __restrict__ hsh,
                          float* __restrict__ acc) {
    int e = blockIdx.x * blockDim.x + threadIdx.x;
    if (e >= N_EDGES) return;
    int r = row[e], c = col[e];
    float w = ew[e];
    float f[8];
    unpack_h8(hsh[r], f);
    float* ap = acc + (size_t)c * 8;
#pragma unroll
    for (int k = 0; k < 8; ++k) atomicAdd(ap + k, w * f[k]);
}
__global__ void f_x2_stats(const float* __restrict__ acc, const float* __restrict__ deg,
                           const float* __restrict__ gcn_b, float* __restrict__ x2,
                           float* __restrict__ stats2) {
    int i = blockIdx.x * blockDim.x + threadIdx.x;
    float vals[8];
    if (i < N_NODES) {
        float di = rsqrtf(fmaxf(deg[i] + 1.0f, EPS_F));
#pragma unroll
        for (int c = 0; c < 8; ++c) {
            float t = di * acc[(size_t)i * 8 + c] + gcn_b[c];
            vals[c] = t;
            x2[(size_t)i * 8 + c] = t;
        }
    } else {
#pragma unroll
        for (int c = 0; c < 8; ++c) vals[c] = 0.f;
    }
    __shared__ float sh[16];
    if (threadIdx.x < 16) sh[threadIdx.x] = 0.f;
    __syncthreads();
#pragma unroll
    for (int c = 0; c < 8; ++c) {
        float s = vals[c], q = vals[c] * vals[c];
#pragma unroll
        for (int off = 32; off > 0; off >>= 1) {
            s += __shfl_down(s, off, 64);
            q += __shfl_down(q, off, 64);
        }
        if ((threadIdx.x & 63) == 0) { atomicAdd(&sh[c], s); atomicAdd(&sh[8 + c], q); }
    }
    __syncthreads();
    if (threadIdx.x < 16) atomicAdd(&stats2[threadIdx.x], sh[threadIdx.x]);
}

extern "C" void kernel_launch(void* const* d_in, const int* in_sizes, int n_in,
                              void* d_out, int out_size, void* d_ws, size_t ws_size,
                              hipStream_t stream) {
    const float* x = (const float*)d_in[0];
    const int* edge_index = (const int*)d_in[1];
    const float* edge_weight = (const float*)d_in[2];
    const float* gru_w_ih = (const float*)d_in[3];
    const float* gru_w_hh = (const float*)d_in[4];
    const float* gru_b_ih = (const float*)d_in[5];
    const float* gru_b_hh = (const float*)d_in[6];
    const float* gn1_w = (const float*)d_in[7];
    const float* gn1_b = (const float*)d_in[8];
    const float* gn1_ms = (const float*)d_in[9];
    const float* gn2_w = (const float*)d_in[10];
    const float* gn2_b = (const float*)d_in[11];
    const float* gn2_ms = (const float*)d_in[12];
    const float* gcn_w = (const float*)d_in[13];
    const float* gcn_b = (const float*)d_in[14];
    const float* fc_w = (const float*)d_in[15];
    const float* fc_b = (const float*)d_in[16];
    float* out = (float*)d_out;

    const int* e_row = edge_index;
    const int* e_col = edge_index + N_EDGES;

    float* ws = (float*)d_ws;
    const size_t N = N_NODES;
    const int BT = 256;
    const int nblk = (N_NODES + BT - 1) / BT;

    // layout (words): stats1[0..18) stats2[18..34) ab1[34..52) ab2[52..68)
    // bcnt_pad[68 .. +NBIN*8) boff[.. +NBIN+1), align4,
    // cmat u16[NCHUNK*NBIN], pmat u16[NCHUNK*NBIN], align4,
    // deg[N], x1_raw[9N] (reused as x2), hsh[4N words], edata[2E words], part[NBKT*SACC*2048]
    const size_t HOFF_BCNT = 68;
    const size_t HOFF_BOFF = HOFF_BCNT + (size_t)NBIN * 8;
    size_t off = HOFF_BOFF + NBIN + 1;
    off = (off + 3) & ~(size_t)3;
    const size_t CMW = ((size_t)NCHUNK * NBIN + 1) / 2;   // u16 pairs -> words
    const size_t OFF_CMAT = off;  off += CMW;
    off = (off + 3) & ~(size_t)3;
    const size_t OFF_PMAT = off;  off += CMW;
    off = (off + 3) & ~(size_t)3;
    const size_t OFF_DEG = off;
    const size_t OFF_X1 = OFF_DEG + N;
    const size_t OFF_HS = (OFF_X1 + 9 * N + 3) & ~(size_t)3;   // uint4-aligned
    const size_t OFF_ED = OFF_HS + 4 * N;
    const size_t OFF_PART = OFF_ED + (size_t)N_EDGES * 2;
    const size_t need1 = (OFF_PART + (size_t)NBKT * SACC * 8 * 256) * 4;

    float* stats1 = ws;
    float* stats2 = ws + 18;
    float* ab1 = ws + 34;
    float* ab2 = ws + 52;

    if (ws_size >= need1) {
        unsigned* bcnt = (unsigned*)(ws + HOFF_BCNT);
        unsigned* boff = (unsigned*)(ws + HOFF_BOFF);
        unsigned short* cmat = (unsigned short*)(ws + OFF_CMAT);
        unsigned short* pmat = (unsigned short*)(ws + OFF_PMAT);
        float* deg = ws + OFF_DEG;
        float* x1_raw = ws + OFF_X1;
        uint4* hsh = (uint4*)(ws + OFF_HS);
        uint2* edata = (uint2*)(ws + OFF_ED);
        float* part = ws + OFF_PART;
        float* x2 = x1_raw;  // x1_raw dead after k_x1_to_hs

        hipMemsetAsync(ws, 0, 68 * sizeof(float), stream);   // stats+ab only
        hipMemsetAsync(deg, 0, N * sizeof(float), stream);

        k_gru<<<nblk, BT, 0, stream>>>(x, gru_w_ih, gru_w_hh, gru_b_ih, gru_b_hh, x1_raw, stats1);
        k_hist2<<<NCHUNK, BT, 0, stream>>>(e_col, cmat);
        k_colscan<<<NBIN, BT, 0, stream>>>(cmat, pmat, bcnt);
        k_scan2<<<1, 1024, 0, stream>>>(bcnt, boff);
        k_place<<<NCHUNK, BT, 0, stream>>>(e_row, e_col, edge_weight, cmat, pmat, boff, edata);
        k_norm_params<<<1, 32, 0, stream>>>(stats1, gn1_w, gn1_b, gn1_ms, ab1, 9);
        k_deg_split<<<NBKT * 4, BT, 0, stream>>>(edata, boff, deg);
        k_x1_to_hs<<<nblk, BT, 0, stream>>>(x1_raw, ab1, gcn_w, deg, hsh);
        k_acc_sp<<<NBKT * SACC, BT, 0, stream>>>(edata, boff, hsh, part);
        k_combine2<<<NBKT, BT, 0, stream>>>(part, hsh, deg, gcn_b, x2, stats2);
        k_norm_params<<<1, 32, 0, stream>>>(stats2, gn2_w, gn2_b, gn2_ms, ab2, 8);
        k_out<<<nblk, BT, 0, stream>>>(x2, ab2, fc_w, fc_b, out);
    } else {
        // tier3: atomic scatter (needs ~22.5N floats)
        float* deg = ws + 68;
        float* x1_raw = deg + N;
        size_t hsoff = (size_t)(68 + N + 9 * N);
        hsoff = (hsoff + 3) & ~(size_t)3;
        uint4* hsh = (uint4*)(ws + hsoff);
        float* acc = ws + hsoff + 4 * N;
        float* x2 = x1_raw;

        hipMemsetAsync(ws, 0, (68 + N) * sizeof(float), stream);

        const int eblk = (N_EDGES + BT - 1) / BT;
        k_gru<<<nblk, BT, 0, stream>>>(x, gru_w_ih, gru_w_hh, gru_b_ih, gru_b_hh, x1_raw, stats1);
        f_deg<<<eblk, BT, 0, stream>>>(e_col, edge_weight, deg);
        k_norm_params<<<1, 32, 0, stream>>>(stats1, gn1_w, gn1_b, gn1_ms, ab1, 9);
        k_x1_to_hs<<<nblk, BT, 0, stream>>>(x1_raw, ab1, gcn_w, deg, hsh);
        f_init_acc<<<nblk, BT, 0, stream>>>(hsh, acc);
        f_scatter<<<eblk, BT, 0, stream>>>(e_row, e_col, edge_weight, hsh, acc);
        f_x2_stats<<<nblk, BT, 0, stream>>>(acc, deg, gcn_b, x2, stats2);
        k_norm_params<<<1, 32, 0, stream>>>(stats2, gn2_w, gn2_b, gn2_ms, ab2, 8);
        k_out<<<nblk, BT, 0, stream>>>(x2, ab2, fc_w, fc_b, out);
    }
}